// Round 1
// baseline (507.000 us; speedup 1.0000x reference)
//
#include <hip/hip_runtime.h>
#include <hip/hip_bf16.h>

// GraphConv: out[t] += sum_e input[sidx[e]] * (esgn[e]*enorm[e]) for tidx[e]==t
// N_NODES=100000, N_FEAT=128, N_EDGES=600000, all fp32.
//
// Baseline strategy: one wave (64 lanes) per edge. Lane l handles features
// [2l, 2l+1] as a float2 -> fully coalesced 512B row gather. Scatter via
// global fp32 atomicAdd (device scope by default on CDNA).

__global__ void graphconv_scatter(const float* __restrict__ input,
                                  const int* __restrict__ sidx,
                                  const int* __restrict__ tidx,
                                  const float* __restrict__ enorm,
                                  const float* __restrict__ esgn,
                                  float* __restrict__ out,
                                  int n_edges) {
    const int gtid   = blockIdx.x * blockDim.x + threadIdx.x;
    const int wave   = gtid >> 6;
    const int lane   = threadIdx.x & 63;
    const int nwaves = (gridDim.x * blockDim.x) >> 6;

    for (int e = wave; e < n_edges; e += nwaves) {
        const int   s = sidx[e];
        const int   t = tidx[e];
        const float w = esgn[e] * enorm[e];

        const float2 v = *reinterpret_cast<const float2*>(input + (size_t)s * 128 + lane * 2);
        float* dst = out + (size_t)t * 128 + lane * 2;
        atomicAdd(dst + 0, v.x * w);
        atomicAdd(dst + 1, v.y * w);
    }
}

extern "C" void kernel_launch(void* const* d_in, const int* in_sizes, int n_in,
                              void* d_out, int out_size, void* d_ws, size_t ws_size,
                              hipStream_t stream) {
    const float* input = (const float*)d_in[0];
    const int*   sidx  = (const int*)d_in[1];
    const int*   tidx  = (const int*)d_in[2];
    const float* enorm = (const float*)d_in[3];
    const float* esgn  = (const float*)d_in[4];
    float*       out   = (float*)d_out;

    const int n_edges = in_sizes[1];

    // Zero the accumulator output (harness poisons it; atomics need zeros).
    hipMemsetAsync(d_out, 0, (size_t)out_size * sizeof(float), stream);

    // 4 waves/block, grid-stride over edges. Cap grid at ~2048 blocks.
    const int block = 256;
    const int waves_needed = n_edges;            // 1 edge per wave per iter
    int grid = (waves_needed * 64 + block - 1) / block;
    if (grid > 2048) grid = 2048;

    graphconv_scatter<<<grid, block, 0, stream>>>(input, sidx, tidx, enorm, esgn,
                                                  out, n_edges);
}

// Round 2
// 126.304 us; speedup vs baseline: 4.0141x; 4.0141x over previous
//
#include <hip/hip_runtime.h>
#include <hip/hip_bf16.h>

// GraphConv: out[t] = sum_{e: tidx[e]==t} input[sidx[e]] * (esgn[e]*enorm[e])
// N_NODES=100000, N_FEAT=128, N_EDGES=600000, fp32.
//
// Round 2 strategy: kill the fp32 atomics on `out` (round-1 bottleneck:
// 614 MB/dispatch of atomic write-through, 507 us).
// Phase A: bin edges by target into fixed-capacity per-node bins (CAP=32,
//          int atomic only on a 400 KB counter array; overflow edges -- which
//          should not occur for Poisson(6) in-degree -- fall back to direct
//          fp32 atomics for correctness).
// Phase B: one wave per node: accumulate its <=CAP edges in registers
//          (float2/lane), single plain float2 store. No fp32 atomics.

#define CAP 32

struct Bin { int src; float w; };   // 8 B

__global__ void scatter_bins(const float* __restrict__ input,
                             const int* __restrict__ sidx,
                             const int* __restrict__ tidx,
                             const float* __restrict__ enorm,
                             const float* __restrict__ esgn,
                             Bin* __restrict__ bins,
                             int* __restrict__ counts,
                             float* __restrict__ out,
                             int n_edges) {
    const int e = blockIdx.x * blockDim.x + threadIdx.x;
    if (e >= n_edges) return;
    const int   t = tidx[e];
    const float w = esgn[e] * enorm[e];
    const int slot = atomicAdd(&counts[t], 1);
    if (slot < CAP) {
        Bin b; b.src = sidx[e]; b.w = w;
        bins[(size_t)t * CAP + slot] = b;
    } else {
        // Rare overflow: direct atomic scatter of the full row (out is zeroed).
        const float* row = input + (size_t)sidx[e] * 128;
        float* dst = out + (size_t)t * 128;
        for (int f = 0; f < 128; ++f) atomicAdd(dst + f, row[f] * w);
    }
}

__global__ void gather_nodes(const float* __restrict__ input,
                             const Bin* __restrict__ bins,
                             const int* __restrict__ counts,
                             float* __restrict__ out,
                             int n_nodes) {
    const int gtid = blockIdx.x * blockDim.x + threadIdx.x;
    const int node = gtid >> 6;
    const int lane = threadIdx.x & 63;
    if (node >= n_nodes) return;

    int cnt = counts[node];
    const bool ovf = cnt > CAP;
    if (ovf) cnt = CAP;

    float2 acc = make_float2(0.f, 0.f);
    const Bin* b = bins + (size_t)node * CAP;
    for (int j = 0; j < cnt; ++j) {
        const Bin bb = b[j];                         // wave-uniform, broadcast
        const float2 v = *reinterpret_cast<const float2*>(
            input + (size_t)bb.src * 128 + lane * 2);
        acc.x += v.x * bb.w;
        acc.y += v.y * bb.w;
    }

    float* dst = out + (size_t)node * 128 + lane * 2;
    if (!ovf) {
        *reinterpret_cast<float2*>(dst) = acc;       // plain store
    } else {
        atomicAdd(dst + 0, acc.x);                   // merge with overflow edges
        atomicAdd(dst + 1, acc.y);
    }
}

// Round-1 fallback (atomic scatter) in case ws is too small for bins.
__global__ void graphconv_scatter(const float* __restrict__ input,
                                  const int* __restrict__ sidx,
                                  const int* __restrict__ tidx,
                                  const float* __restrict__ enorm,
                                  const float* __restrict__ esgn,
                                  float* __restrict__ out,
                                  int n_edges) {
    const int gtid   = blockIdx.x * blockDim.x + threadIdx.x;
    const int wave   = gtid >> 6;
    const int lane   = threadIdx.x & 63;
    const int nwaves = (gridDim.x * blockDim.x) >> 6;
    for (int e = wave; e < n_edges; e += nwaves) {
        const int   s = sidx[e];
        const int   t = tidx[e];
        const float w = esgn[e] * enorm[e];
        const float2 v = *reinterpret_cast<const float2*>(input + (size_t)s * 128 + lane * 2);
        float* dst = out + (size_t)t * 128 + lane * 2;
        atomicAdd(dst + 0, v.x * w);
        atomicAdd(dst + 1, v.y * w);
    }
}

extern "C" void kernel_launch(void* const* d_in, const int* in_sizes, int n_in,
                              void* d_out, int out_size, void* d_ws, size_t ws_size,
                              hipStream_t stream) {
    const float* input = (const float*)d_in[0];
    const int*   sidx  = (const int*)d_in[1];
    const int*   tidx  = (const int*)d_in[2];
    const float* enorm = (const float*)d_in[3];
    const float* esgn  = (const float*)d_in[4];
    float*       out   = (float*)d_out;

    const int n_edges = in_sizes[1];
    const int n_nodes = in_sizes[0] / 128;

    const size_t counts_bytes = (size_t)n_nodes * sizeof(int);
    const size_t counts_pad   = (counts_bytes + 255) & ~(size_t)255;
    const size_t bins_bytes   = (size_t)n_nodes * CAP * sizeof(Bin);

    if (ws_size < counts_pad + bins_bytes) {
        // Fallback: round-1 atomic kernel.
        hipMemsetAsync(d_out, 0, (size_t)out_size * sizeof(float), stream);
        int grid = (n_edges * 64 + 255) / 256;
        if (grid > 2048) grid = 2048;
        graphconv_scatter<<<grid, 256, 0, stream>>>(input, sidx, tidx, enorm, esgn,
                                                    out, n_edges);
        return;
    }

    int* counts = (int*)d_ws;
    Bin* bins   = (Bin*)((char*)d_ws + counts_pad);

    // Zero counters and output (out zero needed for the overflow-atomic path
    // and for zero-in-degree nodes hit by overflow merges).
    hipMemsetAsync(counts, 0, counts_bytes, stream);
    hipMemsetAsync(d_out, 0, (size_t)out_size * sizeof(float), stream);

    const int block = 256;
    const int grid_scatter = (n_edges + block - 1) / block;
    scatter_bins<<<grid_scatter, block, 0, stream>>>(input, sidx, tidx, enorm, esgn,
                                                     bins, counts, out, n_edges);

    const int grid_gather = ((size_t)n_nodes * 64 + block - 1) / block;
    gather_nodes<<<grid_gather, block, 0, stream>>>(input, bins, counts, out, n_nodes);
}

// Round 3
// 95.675 us; speedup vs baseline: 5.2992x; 1.3201x over previous
//
#include <hip/hip_runtime.h>
#include <hip/hip_bf16.h>

// GraphConv: out[t] = sum_{e: tidx[e]==t} input[sidx[e]] * (esgn[e]*enorm[e])
// N_NODES=100000, N_FEAT=128, N_EDGES=600000, fp32.
//
// Round 3: gather_nodes was latency-bound (96us, 26% HBM, 11% VALU).
//  - Unroll gather edge-loop x4 with clamped indices -> 4 bin loads and 4 row
//    loads in flight per step instead of 1+1 (4x fewer latency stalls).
//  - Overflow edges (deg>CAP, ~never for Poisson(6)) go to a side list merged
//    by a fixup kernel AFTER gather's plain stores -> no 51.2MB out memset.

#define CAP 32

struct __align__(8) Bin { int src; float w; };
struct Ovf { int t; int src; float w; };

__global__ void scatter_bins(const int* __restrict__ sidx,
                             const int* __restrict__ tidx,
                             const float* __restrict__ enorm,
                             const float* __restrict__ esgn,
                             Bin* __restrict__ bins,
                             int* __restrict__ counts,
                             Ovf* __restrict__ ovf,
                             int* __restrict__ ovf_count,
                             int ovf_cap,
                             int n_edges) {
    const int e = blockIdx.x * blockDim.x + threadIdx.x;
    if (e >= n_edges) return;
    const int   t = tidx[e];
    const float w = esgn[e] * enorm[e];
    const int slot = atomicAdd(&counts[t], 1);
    if (slot < CAP) {
        Bin b; b.src = sidx[e]; b.w = w;
        bins[(size_t)t * CAP + slot] = b;
    } else {
        const int o = atomicAdd(ovf_count, 1);
        if (o < ovf_cap) { Ovf v; v.t = t; v.src = sidx[e]; v.w = w; ovf[o] = v; }
    }
}

__global__ void gather_nodes(const float* __restrict__ input,
                             const Bin* __restrict__ bins,
                             const int* __restrict__ counts,
                             float* __restrict__ out,
                             int n_nodes) {
    const int node = (blockIdx.x * blockDim.x + threadIdx.x) >> 6;
    const int lane = threadIdx.x & 63;
    if (node >= n_nodes) return;

    const int cnt = min(counts[node], CAP);
    const int off = lane * 2;
    const Bin* __restrict__ b = bins + (size_t)node * CAP;

    float2 acc0 = make_float2(0.f, 0.f);
    float2 acc1 = make_float2(0.f, 0.f);

    for (int j = 0; j < cnt; j += 4) {
        // Clamped indices: always read valid bins; tail lanes get weight 0.
        const int j1 = min(j + 1, cnt - 1);
        const int j2 = min(j + 2, cnt - 1);
        const int j3 = min(j + 3, cnt - 1);
        const Bin b0 = b[j];
        const Bin b1 = b[j1];
        const Bin b2 = b[j2];
        const Bin b3 = b[j3];
        const float w0 = b0.w;
        const float w1 = (j + 1 < cnt) ? b1.w : 0.f;
        const float w2 = (j + 2 < cnt) ? b2.w : 0.f;
        const float w3 = (j + 3 < cnt) ? b3.w : 0.f;
        const float2 v0 = *reinterpret_cast<const float2*>(input + (size_t)b0.src * 128 + off);
        const float2 v1 = *reinterpret_cast<const float2*>(input + (size_t)b1.src * 128 + off);
        const float2 v2 = *reinterpret_cast<const float2*>(input + (size_t)b2.src * 128 + off);
        const float2 v3 = *reinterpret_cast<const float2*>(input + (size_t)b3.src * 128 + off);
        acc0.x += v0.x * w0; acc0.y += v0.y * w0;
        acc1.x += v1.x * w1; acc1.y += v1.y * w1;
        acc0.x += v2.x * w2; acc0.y += v2.y * w2;
        acc1.x += v3.x * w3; acc1.y += v3.y * w3;
    }

    float2 r;
    r.x = acc0.x + acc1.x;
    r.y = acc0.y + acc1.y;
    *reinterpret_cast<float2*>(out + (size_t)node * 128 + off) = r;   // plain store
}

__global__ void fixup_ovf(const float* __restrict__ input,
                          const Ovf* __restrict__ ovf,
                          const int* __restrict__ ovf_count,
                          float* __restrict__ out,
                          int ovf_cap) {
    const int n = min(*ovf_count, ovf_cap);
    const int wave   = (blockIdx.x * blockDim.x + threadIdx.x) >> 6;
    const int lane   = threadIdx.x & 63;
    const int nwaves = (gridDim.x * blockDim.x) >> 6;
    for (int i = wave; i < n; i += nwaves) {
        const Ovf o = ovf[i];
        const float2 v = *reinterpret_cast<const float2*>(input + (size_t)o.src * 128 + lane * 2);
        float* dst = out + (size_t)o.t * 128 + lane * 2;
        atomicAdd(dst + 0, v.x * o.w);
        atomicAdd(dst + 1, v.y * o.w);
    }
}

// Round-1 fallback (atomic scatter) in case ws is too small.
__global__ void graphconv_scatter(const float* __restrict__ input,
                                  const int* __restrict__ sidx,
                                  const int* __restrict__ tidx,
                                  const float* __restrict__ enorm,
                                  const float* __restrict__ esgn,
                                  float* __restrict__ out,
                                  int n_edges) {
    const int gtid   = blockIdx.x * blockDim.x + threadIdx.x;
    const int wave   = gtid >> 6;
    const int lane   = threadIdx.x & 63;
    const int nwaves = (gridDim.x * blockDim.x) >> 6;
    for (int e = wave; e < n_edges; e += nwaves) {
        const float w = esgn[e] * enorm[e];
        const float2 v = *reinterpret_cast<const float2*>(input + (size_t)sidx[e] * 128 + lane * 2);
        float* dst = out + (size_t)tidx[e] * 128 + lane * 2;
        atomicAdd(dst + 0, v.x * w);
        atomicAdd(dst + 1, v.y * w);
    }
}

extern "C" void kernel_launch(void* const* d_in, const int* in_sizes, int n_in,
                              void* d_out, int out_size, void* d_ws, size_t ws_size,
                              hipStream_t stream) {
    const float* input = (const float*)d_in[0];
    const int*   sidx  = (const int*)d_in[1];
    const int*   tidx  = (const int*)d_in[2];
    const float* enorm = (const float*)d_in[3];
    const float* esgn  = (const float*)d_in[4];
    float*       out   = (float*)d_out;

    const int n_edges = in_sizes[1];
    const int n_nodes = in_sizes[0] / 128;

    // ws layout: [counts n_nodes ints][ovf_count 1 int][pad->256][bins][ovf...]
    const size_t zero_bytes = ((size_t)n_nodes + 1) * sizeof(int);
    const size_t bins_off   = (zero_bytes + 255) & ~(size_t)255;
    const size_t bins_bytes = (size_t)n_nodes * CAP * sizeof(Bin);
    const size_t ovf_off    = bins_off + bins_bytes;
    const size_t min_ovf    = 4096 * sizeof(Ovf);

    if (ws_size < ovf_off + min_ovf) {
        hipMemsetAsync(d_out, 0, (size_t)out_size * sizeof(float), stream);
        int grid = (n_edges * 64 + 255) / 256;
        if (grid > 2048) grid = 2048;
        graphconv_scatter<<<grid, 256, 0, stream>>>(input, sidx, tidx, enorm, esgn,
                                                    out, n_edges);
        return;
    }

    int* counts    = (int*)d_ws;
    int* ovf_count = (int*)((char*)d_ws + (size_t)n_nodes * sizeof(int));
    Bin* bins      = (Bin*)((char*)d_ws + bins_off);
    Ovf* ovf       = (Ovf*)((char*)d_ws + ovf_off);
    int  ovf_cap   = (int)((ws_size - ovf_off) / sizeof(Ovf));
    if (ovf_cap > n_edges) ovf_cap = n_edges;

    hipMemsetAsync(counts, 0, zero_bytes, stream);   // counters only (no out memset)

    const int block = 256;
    scatter_bins<<<(n_edges + block - 1) / block, block, 0, stream>>>(
        sidx, tidx, enorm, esgn, bins, counts, ovf, ovf_count, ovf_cap, n_edges);

    gather_nodes<<<(int)(((size_t)n_nodes * 64 + block - 1) / block), block, 0, stream>>>(
        input, bins, counts, out, n_nodes);

    fixup_ovf<<<32, block, 0, stream>>>(input, ovf, ovf_count, out, ovf_cap);
}